// Round 1
// baseline (1205.101 us; speedup 1.0000x reference)
//
#include <hip/hip_runtime.h>
#include <cmath>

#define NDOF 7
#define HID  256
#define SPW  8            // samples per workgroup
#define NCOL 64           // SPW * 8 columns (primal + 7 tangents)

__device__ __forceinline__ float softplus_f(float x){
    return fmaxf(x, 0.0f) + log1pf(expf(-fabsf(x)));
}
__device__ __forceinline__ float sigmoid_f(float x){
    return 1.0f / (1.0f + expf(-x));
}

__launch_bounds__(256, 2)
__global__ void dln_kernel(
    const float* __restrict__ q,  const float* __restrict__ qd, const float* __restrict__ qdd,
    const float* __restrict__ W0, const float* __restrict__ b0,
    const float* __restrict__ W1, const float* __restrict__ b1,
    const float* __restrict__ W2, const float* __restrict__ b2,
    const float* __restrict__ Wg, const float* __restrict__ bg,
    const float* __restrict__ Wld,const float* __restrict__ bld,
    const float* __restrict__ Wlt,const float* __restrict__ blt,
    const float* __restrict__ fd, const float* __restrict__ fc,
    const float* __restrict__ fs, const float* __restrict__ fv,
    float* __restrict__ out, int Btot)
{
    // X[k][c]: activations+tangents, row k contiguous over 64 cols (c = s*8 + {0:h, 1..7:dq})
    __shared__ float X[HID*NCOL];      // 64 KB
    __shared__ float SCR[35*64];       // 8.75 KB: Wt[8][256] during GEMMs, Yh[35][64] after
    __shared__ float qs[SPW][NDOF], qds[SPW][NDOF], qdds[SPW][NDOF];
    __shared__ float Ls[SPW][7][7], vs[SPW][7][7], ldts[SPW][7][7];
    __shared__ float ubuf[SPW][8], wbuf[SPW][8], sgld[SPW][8], ldraw_s[SPW][8];

    const int tid = threadIdx.x;
    const int s0g = blockIdx.x * SPW;

    if (tid < SPW*NDOF){
        int s = tid / NDOF, d = tid % NDOF;
        qs[s][d]   = q  [(s0g+s)*NDOF + d];
        qds[s][d]  = qd [(s0g+s)*NDOF + d];
        qdds[s][d] = qdd[(s0g+s)*NDOF + d];
    }
    __syncthreads();

    // ---------------- layer 0: thread = hidden row m ----------------
    {
        float w0r[NDOF];
        #pragma unroll
        for (int d=0; d<NDOF; ++d) w0r[d] = W0[tid*NDOF + d];
        float b0v = b0[tid];
        #pragma unroll
        for (int s=0; s<SPW; ++s){
            float z = b0v;
            #pragma unroll
            for (int d=0; d<NDOF; ++d) z = fmaf(w0r[d], qs[s][d], z);
            float h = softplus_f(z), sg = sigmoid_f(z);
            float* xr = &X[tid*NCOL + s*8];
            xr[0] = h;
            #pragma unroll
            for (int d=0; d<NDOF; ++d) xr[1+d] = sg * w0r[d];
        }
    }
    __syncthreads();

    const int tc = tid & 7;    // sample (column block of 8)
    const int tm = tid >> 3;   // row block (0..31), rows m = tm*8+i

    // ---------------- hidden layers 1,2: Y = act(W @ X + b) ----------------
    #define HIDDEN_LAYER(Wp, bp) { \
        float acc[8][8]; \
        _Pragma("unroll") for (int i=0;i<8;++i) _Pragma("unroll") for (int j=0;j<8;++j) acc[i][j]=0.f; \
        for (int kb=0; kb<32; ++kb){ \
            const float4* wsrc = reinterpret_cast<const float4*>(Wp + tid*HID + kb*8); \
            float4 wv0 = wsrc[0], wv1 = wsrc[1]; \
            __syncthreads(); \
            SCR[0*HID+tid]=wv0.x; SCR[1*HID+tid]=wv0.y; SCR[2*HID+tid]=wv0.z; SCR[3*HID+tid]=wv0.w; \
            SCR[4*HID+tid]=wv1.x; SCR[5*HID+tid]=wv1.y; SCR[6*HID+tid]=wv1.z; SCR[7*HID+tid]=wv1.w; \
            __syncthreads(); \
            _Pragma("unroll") for (int j=0;j<8;++j){ \
                float4 a0 = *reinterpret_cast<const float4*>(&SCR[j*HID + tm*8]); \
                float4 a1 = *reinterpret_cast<const float4*>(&SCR[j*HID + tm*8 + 4]); \
                float4 x0 = *reinterpret_cast<const float4*>(&X[(kb*8+j)*NCOL + tc*8]); \
                float4 x1 = *reinterpret_cast<const float4*>(&X[(kb*8+j)*NCOL + tc*8 + 4]); \
                float av[8] = {a0.x,a0.y,a0.z,a0.w,a1.x,a1.y,a1.z,a1.w}; \
                float xv[8] = {x0.x,x0.y,x0.z,x0.w,x1.x,x1.y,x1.z,x1.w}; \
                _Pragma("unroll") for (int i=0;i<8;++i) \
                    _Pragma("unroll") for (int jj=0;jj<8;++jj) \
                        acc[i][jj] = fmaf(av[i], xv[jj], acc[i][jj]); \
            } \
        } \
        __syncthreads(); \
        _Pragma("unroll") for (int i=0;i<8;++i){ \
            float z = acc[i][0] + bp[tm*8+i]; \
            float h = softplus_f(z), sg = sigmoid_f(z); \
            float* xr = &X[(tm*8+i)*NCOL + tc*8]; \
            xr[0] = h; \
            _Pragma("unroll") for (int j=1;j<8;++j) xr[j] = sg*acc[i][j]; \
        } \
        __syncthreads(); \
    }

    HIDDEN_LAYER(W1, b1);
    HIDDEN_LAYER(W2, b2);

    // ---------------- heads: Yh[35][64] = [Wg;Wld;Wlt] @ X2 (biases added in tail) ----------------
    {
        int rg = tid >> 6;          // one wave per row-group (scalar W addresses)
        int c  = tid & 63;
        int r0 = rg * 9;
        int nr = (rg < 3) ? 9 : 8;  // 9+9+9+8 = 35
        for (int rr=0; rr<nr; ++rr){
            int r = r0 + rr;
            const float* wr = (r<7) ? (Wg + r*HID) : (r<14) ? (Wld + (r-7)*HID) : (Wlt + (r-14)*HID);
            const float4* wr4 = reinterpret_cast<const float4*>(wr);
            float a = 0.f;
            #pragma unroll 8
            for (int k4=0; k4<64; ++k4){
                float4 w = wr4[k4];
                a = fmaf(w.x, X[(k4*4+0)*NCOL + c], a);
                a = fmaf(w.y, X[(k4*4+1)*NCOL + c], a);
                a = fmaf(w.z, X[(k4*4+2)*NCOL + c], a);
                a = fmaf(w.w, X[(k4*4+3)*NCOL + c], a);
            }
            SCR[r*64 + c] = a;
        }
    }
    __syncthreads();

    // ---------------- analytic tail, 32 threads/sample (7 active lanes) ----------------
    {
        const int s  = tid >> 5;
        const int l  = tid & 31;
        const int cb = s * 8;

        if (l < 7){
            int i = l;
            float lr = SCR[(7+i)*64 + cb] + bld[i];
            ldraw_s[s][i] = lr;
            sgld[s][i] = sigmoid_f(lr);
            for (int j=0;j<7;++j){
                float val;
                if (j == i)      val = softplus_f(lr) + 1e-3f;
                else if (j < i)  val = SCR[(14 + (i*(i-1))/2 + j)*64 + cb] + blt[(i*(i-1))/2 + j];
                else             val = 0.f;
                Ls[s][i][j] = val;
            }
        }
        __syncthreads();

        // L_dq[i][j][c] accessor from head outputs
        auto LDQ = [&](int i, int j, int c)->float{
            if (i == j) return sgld[s][i] * SCR[(7+i)*64 + cb + 1 + c];
            if (i >  j) return SCR[(14 + (i*(i-1))/2 + j)*64 + cb + 1 + c];
            return 0.f;
        };

        if (l < 7){
            // u[m] = sum_j qd_j L[j][m]   (m = l)
            float u = 0.f;
            for (int j=0;j<7;++j) u = fmaf(qds[s][j], Ls[s][j][l], u);
            ubuf[s][l] = u;
            // v[m][c] = sum_j qd_j L_dq[j][m][c]   (c = l)
            for (int m=0;m<7;++m){
                float v = 0.f;
                for (int j=0;j<7;++j) v = fmaf(qds[s][j], LDQ(j,m,l), v);
                vs[s][m][l] = v;
            }
            // L_dt[i][k] = sum_c L_dq[i][k][c] qd_c   (i = l)
            for (int k=0;k<7;++k){
                float a = 0.f;
                for (int c2=0;c2<7;++c2) a = fmaf(LDQ(l,k,c2), qds[s][c2], a);
                ldts[s][l][k] = a;
            }
        }
        __syncthreads();

        if (l < 7){
            // w2[k] = sum_c v[k][c] qd_c   (k = l)
            float w2 = 0.f;
            for (int c2=0;c2<7;++c2) w2 = fmaf(vs[s][l][c2], qds[s][c2], w2);
            wbuf[s][l] = w2;
        }
        __syncthreads();

        if (l < 7){
            const int i  = l;
            const int Sg = s0g + s;
            // c1[i] = sum_k L[i][k] w2[k] + L_dt[i][k] u[k]
            float c1 = 0.f;
            for (int k=0;k<7;++k)
                c1 += Ls[s][i][k]*wbuf[s][k] + ldts[s][i][k]*ubuf[s][k];
            // qd^T H_dq qd [i] = 2 * sum_m u[m] v[m][i];  c -= 0.5 * that
            float qh = 0.f;
            for (int m=0;m<7;++m) qh = fmaf(ubuf[s][m], vs[s][m][i], qh);
            float cfin = c1 - qh;
            // Hm row i
            float hm[7];
            for (int j=0;j<7;++j){
                float a = 0.f;
                for (int k=0;k<7;++k) a = fmaf(Ls[s][i][k], Ls[s][j][k], a);
                hm[j] = a;
            }
            float gv  = SCR[i*64 + cb] + bg[i];
            float qdv = qds[s][i];
            float fvc = fmaxf(fv[i], 1e-3f);
            float tf  = (fc[i] + fs[i]*expf(-qdv*qdv/fvc))*tanhf(100.0f*qdv) + fd[i]*qdv;
            float tp  = cfin + gv + tf;
            for (int j=0;j<7;++j) tp = fmaf(hm[j], qdds[s][j], tp);

            const int B = Btot;
            out[Sg*7 + i] = tp;                                    // tau_pred
            float* o1 = out + (size_t)B*7;                         // Hm
            for (int j=0;j<7;++j) o1[(size_t)Sg*49 + i*7 + j] = hm[j];
            out[(size_t)B*56 + Sg*7 + i] = cfin;                   // c
            out[(size_t)B*63 + Sg*7 + i] = gv;                     // g
            out[(size_t)B*70 + Sg*7 + i] = tf;                     // tau_fric
            out[(size_t)B*77 + Sg*7 + i] = ldraw_s[s][i];          // Ld_raw
        }
    }
}

extern "C" void kernel_launch(void* const* d_in, const int* in_sizes, int n_in,
                              void* d_out, int out_size, void* d_ws, size_t ws_size,
                              hipStream_t stream) {
    const float* q   = (const float*)d_in[0];
    const float* qd  = (const float*)d_in[1];
    const float* qdd = (const float*)d_in[2];
    const float* W0  = (const float*)d_in[3];
    const float* b0  = (const float*)d_in[4];
    const float* W1  = (const float*)d_in[5];
    const float* b1  = (const float*)d_in[6];
    const float* W2  = (const float*)d_in[7];
    const float* b2  = (const float*)d_in[8];
    const float* Wg  = (const float*)d_in[9];
    const float* bg  = (const float*)d_in[10];
    const float* Wld = (const float*)d_in[11];
    const float* bld = (const float*)d_in[12];
    const float* Wlt = (const float*)d_in[13];
    const float* blt = (const float*)d_in[14];
    const float* fd  = (const float*)d_in[15];
    const float* fc  = (const float*)d_in[16];
    const float* fs  = (const float*)d_in[17];
    const float* fv  = (const float*)d_in[18];

    const int Btot = in_sizes[0] / NDOF;      // 32768
    dim3 grid(Btot / SPW), block(256);
    dln_kernel<<<grid, block, 0, stream>>>(q, qd, qdd, W0, b0, W1, b1, W2, b2,
                                           Wg, bg, Wld, bld, Wlt, blt,
                                           fd, fc, fs, fv,
                                           (float*)d_out, Btot);
}

// Round 2
// 283.478 us; speedup vs baseline: 4.2511x; 4.2511x over previous
//
#include <hip/hip_runtime.h>
#include <cmath>

#define NDOF 7
#define HID  256
#define SPW  8            // samples per workgroup
#define NCOL 64           // 8 primal cols (0..7) + 56 tangent cols (8 + s*7 + d)

typedef __bf16 bf16x8 __attribute__((ext_vector_type(8)));
typedef float  f32x4  __attribute__((ext_vector_type(4)));

__device__ __forceinline__ float softplus_fast(float x){
    float e = __expf(-fabsf(x));
    return fmaxf(x, 0.0f) + __logf(1.0f + e);
}
__device__ __forceinline__ float sigmoid_fast(float x){
    float e  = __expf(-fabsf(x));
    float rc = 1.0f / (1.0f + e);
    return (x >= 0.0f) ? rc : e * rc;
}
__device__ __forceinline__ float tanh_fast(float y){ // tanh(y)
    float e2 = __expf(-2.0f * fabsf(y));
    float t  = (1.0f - e2) / (1.0f + e2);
    return (y >= 0.0f) ? t : -t;
}

// ---- weight prep: f32 -> bf16, heads packed into 48x256 (rows 35..47 zero) ----
__global__ void convert_weights(const float* __restrict__ W1, const float* __restrict__ W2,
                                const float* __restrict__ Wg, const float* __restrict__ Wld,
                                const float* __restrict__ Wlt, __bf16* __restrict__ ws)
{
    int i = blockIdx.x * 256 + threadIdx.x;          // 0 .. 143360
    if (i < 65536)        ws[i] = (__bf16)W1[i];
    else if (i < 131072)  ws[i] = (__bf16)W2[i - 65536];
    else if (i < 143360) {
        int j = i - 131072;
        int r = j >> 8, k = j & 255;
        float v = 0.0f;
        if (r < 7)       v = Wg [r * HID + k];
        else if (r < 14) v = Wld[(r - 7) * HID + k];
        else if (r < 35) v = Wlt[(r - 14) * HID + k];
        ws[i] = (__bf16)v;
    }
}

__launch_bounds__(256, 2)
__global__ void dln_main(
    const float* __restrict__ q,  const float* __restrict__ qd, const float* __restrict__ qdd,
    const float* __restrict__ W0, const float* __restrict__ b0,
    const float* __restrict__ b1, const float* __restrict__ b2,
    const float* __restrict__ bg, const float* __restrict__ bld, const float* __restrict__ blt,
    const float* __restrict__ fd, const float* __restrict__ fc,
    const float* __restrict__ fs, const float* __restrict__ fv,
    const __bf16* __restrict__ wsb,
    float* __restrict__ out, int Btot)
{
    // X col-major: Xs[col*256 + (k ^ ((col&7)<<3))], bf16
    __shared__ __bf16 Xs[NCOL * HID];                 // 32 KB
    __shared__ float  SCR[35 * 64];                   // head outputs (raw, biases in tail)
    __shared__ float  qs[SPW][NDOF], qds[SPW][NDOF], qdds[SPW][NDOF];
    __shared__ float  Ls[SPW][7][7], vsh[SPW][7][7], ldts[SPW][7][7];
    __shared__ float  ubuf[SPW][8], wbuf[SPW][8], sgld[SPW][8], ldraw_s[SPW][8];

    const int tid = threadIdx.x;
    const int w   = tid >> 6;        // wave 0..3
    const int l   = tid & 63;
    const int lo  = l & 15;
    const int hi  = l >> 4;
    const int s0g = blockIdx.x * SPW;

    if (tid < SPW * NDOF){
        int s = tid / NDOF, d = tid % NDOF;
        qs[s][d]   = q  [(s0g + s) * NDOF + d];
        qds[s][d]  = qd [(s0g + s) * NDOF + d];
        qdds[s][d] = qdd[(s0g + s) * NDOF + d];
    }

    // per-lane column decode for the 4 N-tiles
    int  srcl[4]; bool isprim[4];
    #pragma unroll
    for (int ni = 0; ni < 4; ++ni){
        int col   = ni * 16 + lo;
        int s     = (col < 8) ? col : (col - 8) / 7;
        srcl[ni]  = (l & ~15) | s;
        isprim[ni]= (col < 8);
    }
    __syncthreads();

    // ---------------- layer 0 (VALU, tiny K=7): thread = hidden row m ----------------
    {
        float w0r[NDOF];
        #pragma unroll
        for (int d = 0; d < NDOF; ++d) w0r[d] = W0[tid * NDOF + d];
        float b0v = b0[tid];
        #pragma unroll
        for (int s = 0; s < SPW; ++s){
            float z = b0v;
            #pragma unroll
            for (int d = 0; d < NDOF; ++d) z = fmaf(w0r[d], qs[s][d], z);
            float h = softplus_fast(z), sg = sigmoid_fast(z);
            Xs[s * HID + (tid ^ ((s & 7) << 3))] = (__bf16)h;
            #pragma unroll
            for (int d = 0; d < NDOF; ++d){
                int col = 8 + s * 7 + d;
                Xs[col * HID + (tid ^ ((col & 7) << 3))] = (__bf16)(sg * w0r[d]);
            }
        }
    }
    __syncthreads();

    // ---------------- hidden layers via MFMA ----------------
    auto hidden_layer = [&](const __bf16* __restrict__ Wb, const float* __restrict__ bp){
        f32x4 acc[4][4];
        #pragma unroll
        for (int mi = 0; mi < 4; ++mi)
            #pragma unroll
            for (int ni = 0; ni < 4; ++ni) acc[mi][ni] = (f32x4){0.f,0.f,0.f,0.f};

        #pragma unroll 2
        for (int kk = 0; kk < 8; ++kk){
            const int k0 = kk * 32 + hi * 8;
            bf16x8 a[4], bfr[4];
            #pragma unroll
            for (int mi = 0; mi < 4; ++mi)
                a[mi] = *reinterpret_cast<const bf16x8*>(Wb + (w * 64 + mi * 16 + lo) * HID + k0);
            #pragma unroll
            for (int ni = 0; ni < 4; ++ni){
                int col = ni * 16 + lo;
                bfr[ni] = *reinterpret_cast<const bf16x8*>(Xs + col * HID + (k0 ^ ((col & 7) << 3)));
            }
            #pragma unroll
            for (int mi = 0; mi < 4; ++mi)
                #pragma unroll
                for (int ni = 0; ni < 4; ++ni)
                    acc[mi][ni] = __builtin_amdgcn_mfma_f32_16x16x32_bf16(a[mi], bfr[ni], acc[mi][ni], 0, 0, 0);
        }
        __syncthreads();   // all Xs reads complete before overwrite

        #pragma unroll
        for (int mi = 0; mi < 4; ++mi){
            const int row0 = w * 64 + mi * 16 + hi * 4;
            float4 b4 = *reinterpret_cast<const float4*>(bp + row0);
            float h[4], sg[4];
            #pragma unroll
            for (int r = 0; r < 4; ++r){
                float z  = acc[mi][0][r] + ((const float*)&b4)[r];
                float e  = __expf(-fabsf(z));
                float rc = 1.0f / (1.0f + e);
                h[r]  = fmaxf(z, 0.0f) + __logf(1.0f + e);
                sg[r] = (z >= 0.0f) ? rc : e * rc;
            }
            #pragma unroll
            for (int ni = 0; ni < 4; ++ni){
                int col = ni * 16 + lo;
                union { uint2 u2; __bf16 b[4]; } pk;
                #pragma unroll
                for (int r = 0; r < 4; ++r){
                    float sgb = __shfl(sg[r], srcl[ni]);
                    float v   = isprim[ni] ? h[r] : sgb * acc[mi][ni][r];
                    pk.b[r] = (__bf16)v;
                }
                *reinterpret_cast<uint2*>(Xs + col * HID + (row0 ^ ((col & 7) << 3))) = pk.u2;
            }
        }
        __syncthreads();
    };

    hidden_layer(wsb,           b1);
    hidden_layer(wsb + 65536,   b2);

    // ---------------- heads via MFMA: [48 x 256] @ X -> SCR[35][64] ----------------
    {
        const __bf16* Wh = wsb + 131072;
        if (w < 3){
            f32x4 hacc[4];
            #pragma unroll
            for (int ni = 0; ni < 4; ++ni) hacc[ni] = (f32x4){0.f,0.f,0.f,0.f};
            #pragma unroll 2
            for (int kk = 0; kk < 8; ++kk){
                const int k0 = kk * 32 + hi * 8;
                bf16x8 a = *reinterpret_cast<const bf16x8*>(Wh + (w * 16 + lo) * HID + k0);
                #pragma unroll
                for (int ni = 0; ni < 4; ++ni){
                    int col = ni * 16 + lo;
                    bf16x8 bfr = *reinterpret_cast<const bf16x8*>(Xs + col * HID + (k0 ^ ((col & 7) << 3)));
                    hacc[ni] = __builtin_amdgcn_mfma_f32_16x16x32_bf16(a, bfr, hacc[ni], 0, 0, 0);
                }
            }
            #pragma unroll
            for (int ni = 0; ni < 4; ++ni)
                #pragma unroll
                for (int r = 0; r < 4; ++r){
                    int row = w * 16 + hi * 4 + r;
                    if (row < 35) SCR[row * 64 + ni * 16 + lo] = hacc[ni][r];
                }
        }
    }
    __syncthreads();

    // ---------------- analytic tail: 8 groups of 32 lanes, sample s = tid>>5 ----------------
    {
        const int s = tid >> 5;
        const int t = tid & 31;

        if (t < 7){
            int i = t;
            float lr = SCR[(7 + i) * 64 + s] + bld[i];
            ldraw_s[s][i] = lr;
            sgld[s][i]    = sigmoid_fast(lr);
            for (int j = 0; j < 7; ++j){
                float val;
                if (j == i)      val = softplus_fast(lr) + 1e-3f;
                else if (j < i)  val = SCR[(14 + (i*(i-1))/2 + j) * 64 + s] + blt[(i*(i-1))/2 + j];
                else             val = 0.f;
                Ls[s][i][j] = val;
            }
        }
        __syncthreads();

        auto LDQ = [&](int i, int j, int c)->float{
            if (i == j) return sgld[s][i] * SCR[(7 + i) * 64 + 8 + s * 7 + c];
            if (i >  j) return SCR[(14 + (i*(i-1))/2 + j) * 64 + 8 + s * 7 + c];
            return 0.f;
        };

        if (t < 7){
            float u = 0.f;
            for (int j = 0; j < 7; ++j) u = fmaf(qds[s][j], Ls[s][j][t], u);
            ubuf[s][t] = u;
            for (int m = 0; m < 7; ++m){
                float v = 0.f;
                for (int j = 0; j < 7; ++j) v = fmaf(qds[s][j], LDQ(j, m, t), v);
                vsh[s][m][t] = v;
            }
            for (int k = 0; k < 7; ++k){
                float a = 0.f;
                for (int c2 = 0; c2 < 7; ++c2) a = fmaf(LDQ(t, k, c2), qds[s][c2], a);
                ldts[s][t][k] = a;
            }
        }
        __syncthreads();

        if (t < 7){
            float w2 = 0.f;
            for (int c2 = 0; c2 < 7; ++c2) w2 = fmaf(vsh[s][t][c2], qds[s][c2], w2);
            wbuf[s][t] = w2;
        }
        __syncthreads();

        if (t < 7){
            const int i  = t;
            const int Sg = s0g + s;
            float c1 = 0.f;
            for (int k = 0; k < 7; ++k)
                c1 += Ls[s][i][k] * wbuf[s][k] + ldts[s][i][k] * ubuf[s][k];
            float qh = 0.f;
            for (int m = 0; m < 7; ++m) qh = fmaf(ubuf[s][m], vsh[s][m][i], qh);
            float cfin = c1 - qh;
            float hm[7];
            for (int j = 0; j < 7; ++j){
                float a = 0.f;
                for (int k = 0; k < 7; ++k) a = fmaf(Ls[s][i][k], Ls[s][j][k], a);
                hm[j] = a;
            }
            float gv  = SCR[i * 64 + s] + bg[i];
            float qdv = qds[s][i];
            float fvc = fmaxf(fv[i], 1e-3f);
            float tf  = (fc[i] + fs[i] * __expf(-qdv * qdv / fvc)) * tanh_fast(100.0f * qdv) + fd[i] * qdv;
            float tp  = cfin + gv + tf;
            for (int j = 0; j < 7; ++j) tp = fmaf(hm[j], qdds[s][j], tp);

            const int B = Btot;
            out[Sg * 7 + i] = tp;
            float* o1 = out + (size_t)B * 7;
            for (int j = 0; j < 7; ++j) o1[(size_t)Sg * 49 + i * 7 + j] = hm[j];
            out[(size_t)B * 56 + Sg * 7 + i] = cfin;
            out[(size_t)B * 63 + Sg * 7 + i] = gv;
            out[(size_t)B * 70 + Sg * 7 + i] = tf;
            out[(size_t)B * 77 + Sg * 7 + i] = ldraw_s[s][i];
        }
    }
}

extern "C" void kernel_launch(void* const* d_in, const int* in_sizes, int n_in,
                              void* d_out, int out_size, void* d_ws, size_t ws_size,
                              hipStream_t stream) {
    const float* q   = (const float*)d_in[0];
    const float* qd  = (const float*)d_in[1];
    const float* qdd = (const float*)d_in[2];
    const float* W0  = (const float*)d_in[3];
    const float* b0  = (const float*)d_in[4];
    const float* W1  = (const float*)d_in[5];
    const float* b1  = (const float*)d_in[6];
    const float* W2  = (const float*)d_in[7];
    const float* b2  = (const float*)d_in[8];
    const float* Wg  = (const float*)d_in[9];
    const float* bg  = (const float*)d_in[10];
    const float* Wld = (const float*)d_in[11];
    const float* bld = (const float*)d_in[12];
    const float* Wlt = (const float*)d_in[13];
    const float* blt = (const float*)d_in[14];
    const float* fd  = (const float*)d_in[15];
    const float* fc  = (const float*)d_in[16];
    const float* fs  = (const float*)d_in[17];
    const float* fv  = (const float*)d_in[18];

    const int Btot = in_sizes[0] / NDOF;      // 32768
    __bf16* wsb = (__bf16*)d_ws;

    convert_weights<<<dim3(560), dim3(256), 0, stream>>>(W1, W2, Wg, Wld, Wlt, wsb);
    dln_main<<<dim3(Btot / SPW), dim3(256), 0, stream>>>(q, qd, qdd, W0, b0,
                                                         b1, b2, bg, bld, blt,
                                                         fd, fc, fs, fv,
                                                         wsb, (float*)d_out, Btot);
}

// Round 3
// 267.355 us; speedup vs baseline: 4.5075x; 1.0603x over previous
//
#include <hip/hip_runtime.h>
#include <cmath>

#define NDOF 7
#define HID  256
#define SPW  8            // samples per workgroup
#define NCOL 64           // 8 primal cols (0..7) + 56 tangent cols (8 + s*7 + d)

typedef __bf16 bf16x8 __attribute__((ext_vector_type(8)));
typedef float  f32x4  __attribute__((ext_vector_type(4)));

// ws layout (bf16 elems): W1b@0 (65536), W2b@65536, Whb@131072 (48x256), W0b@143360 (256x32, K-padded)
#define OFF_W2 65536
#define OFF_WH 131072
#define OFF_W0 143360
#define WS_TOT 151552

__device__ __forceinline__ float softplus_fast(float x){
    float e = __expf(-fabsf(x));
    return fmaxf(x, 0.0f) + __logf(1.0f + e);
}
__device__ __forceinline__ float sigmoid_fast(float x){
    float e  = __expf(-fabsf(x));
    float rc = 1.0f / (1.0f + e);
    return (x >= 0.0f) ? rc : e * rc;
}
__device__ __forceinline__ float tanh_fast(float y){
    float e2 = __expf(-2.0f * fabsf(y));
    float t  = (1.0f - e2) / (1.0f + e2);
    return (y >= 0.0f) ? t : -t;
}

__global__ void convert_weights(const float* __restrict__ W1, const float* __restrict__ W2,
                                const float* __restrict__ Wg, const float* __restrict__ Wld,
                                const float* __restrict__ Wlt, const float* __restrict__ W0,
                                __bf16* __restrict__ ws)
{
    int i = blockIdx.x * 256 + threadIdx.x;
    if (i < OFF_W2)        ws[i] = (__bf16)W1[i];
    else if (i < OFF_WH)   ws[i] = (__bf16)W2[i - OFF_W2];
    else if (i < OFF_W0) {
        int j = i - OFF_WH;
        int r = j >> 8, k = j & 255;
        float v = 0.0f;
        if (r < 7)       v = Wg [r * HID + k];
        else if (r < 14) v = Wld[(r - 7) * HID + k];
        else if (r < 35) v = Wlt[(r - 14) * HID + k];
        ws[i] = (__bf16)v;
    } else if (i < WS_TOT) {
        int j = i - OFF_W0;
        int r = j >> 5, k = j & 31;
        ws[i] = (__bf16)((k < 7) ? W0[r * 7 + k] : 0.0f);
    }
}

// one MLP layer: acc = Wb @ Xs (K = KK*32), epilogue softplus/sigmoid-tangent, write back to Xs
template<int KK>
__device__ __forceinline__ void mlp_layer(
    const __bf16* __restrict__ Wb, int astride, const float* __restrict__ bp,
    __bf16* Xs, __bf16 (*sgbuf)[264],
    int w, int lo, int hi, const int* scol, bool prim)
{
    f32x4 acc[4][4];
    #pragma unroll
    for (int mi = 0; mi < 4; ++mi)
        #pragma unroll
        for (int ni = 0; ni < 4; ++ni) acc[mi][ni] = (f32x4){0.f,0.f,0.f,0.f};

    #pragma unroll 2
    for (int kk = 0; kk < KK; ++kk){
        const int k0 = kk * 32 + hi * 8;
        bf16x8 a[4], bfr[4];
        #pragma unroll
        for (int mi = 0; mi < 4; ++mi)
            a[mi] = *reinterpret_cast<const bf16x8*>(Wb + (w * 64 + mi * 16 + lo) * astride + k0);
        #pragma unroll
        for (int ni = 0; ni < 4; ++ni){
            int col = ni * 16 + lo;
            bfr[ni] = *reinterpret_cast<const bf16x8*>(Xs + col * HID + (k0 ^ ((col & 7) << 3)));
        }
        #pragma unroll
        for (int mi = 0; mi < 4; ++mi)
            #pragma unroll
            for (int ni = 0; ni < 4; ++ni)
                acc[mi][ni] = __builtin_amdgcn_mfma_f32_16x16x32_bf16(a[mi], bfr[ni], acc[mi][ni], 0, 0, 0);
    }
    __syncthreads();   // all Xs reads complete before overwrite

    float h[4][4];
    #pragma unroll
    for (int mi = 0; mi < 4; ++mi){
        const int row0 = w * 64 + mi * 16 + hi * 4;
        float4 b4 = *reinterpret_cast<const float4*>(bp + row0);
        union { uint2 u2; __bf16 b[4]; } sp;
        #pragma unroll
        for (int r = 0; r < 4; ++r){
            float z  = acc[mi][0][r] + ((const float*)&b4)[r];
            float e  = __expf(-fabsf(z));
            float rc = 1.0f / (1.0f + e);
            h[mi][r] = fmaxf(z, 0.0f) + __logf(1.0f + e);
            sp.b[r]  = (__bf16)((z >= 0.0f) ? rc : e * rc);
        }
        if (lo < 8) *reinterpret_cast<uint2*>(&sgbuf[lo][row0]) = sp.u2;
    }
    asm volatile("s_waitcnt lgkmcnt(0)" ::: "memory");

    #pragma unroll
    for (int mi = 0; mi < 4; ++mi){
        const int row0 = w * 64 + mi * 16 + hi * 4;
        #pragma unroll
        for (int ni = 0; ni < 4; ++ni){
            union { uint2 u2; __bf16 b[4]; } sg;
            sg.u2 = *reinterpret_cast<const uint2*>(&sgbuf[scol[ni]][row0]);
            int col = ni * 16 + lo;
            union { uint2 u2; __bf16 b[4]; } pk;
            #pragma unroll
            for (int r = 0; r < 4; ++r){
                float v = (ni == 0 && prim) ? h[mi][r] : (float)sg.b[r] * acc[mi][ni][r];
                pk.b[r] = (__bf16)v;
            }
            *reinterpret_cast<uint2*>(Xs + col * HID + (row0 ^ ((col & 7) << 3))) = pk.u2;
        }
    }
    __syncthreads();
}

__launch_bounds__(256, 4)
__global__ void dln_main(
    const float* __restrict__ q,  const float* __restrict__ qd, const float* __restrict__ qdd,
    const float* __restrict__ b0, const float* __restrict__ b1, const float* __restrict__ b2,
    const float* __restrict__ bg, const float* __restrict__ bld, const float* __restrict__ blt,
    const float* __restrict__ fd, const float* __restrict__ fc,
    const float* __restrict__ fs, const float* __restrict__ fv,
    const __bf16* __restrict__ wsb,
    float* __restrict__ out, int Btot)
{
    __shared__ __align__(16) unsigned char LDSB[32768];   // Xs, later SCR + tail scratch
    __shared__ __bf16 sgbuf[SPW][264];
    __shared__ float  qs[SPW][NDOF], qds_[SPW][NDOF], qdds_[SPW][NDOF];

    __bf16* Xs = (__bf16*)LDSB;

    const int tid = threadIdx.x;
    const int w   = tid >> 6;
    const int l   = tid & 63;
    const int lo  = l & 15;
    const int hi  = l >> 4;
    const int s0g = blockIdx.x * SPW;
    const bool prim = (lo < 8);

    if (tid < SPW * NDOF){
        int s = tid / NDOF, d = tid % NDOF;
        qs[s][d]    = q  [(s0g + s) * NDOF + d];
        qds_[s][d]  = qd [(s0g + s) * NDOF + d];
        qdds_[s][d] = qdd[(s0g + s) * NDOF + d];
    }

    int scol[4];
    #pragma unroll
    for (int ni = 0; ni < 4; ++ni){
        int col  = ni * 16 + lo;
        scol[ni] = (col < 8) ? col : (col - 8) / 7;
    }

    // ---- build B0 = [q | I] (zero-padded to K=32) in Xs, swizzled ----
    {
        int col = tid >> 2, part = tid & 3;     // zero phys k 0..63 of each col
        uint4 z4 = {0,0,0,0};
        *reinterpret_cast<uint4*>(Xs + col * HID + part * 16)     = z4;
        *reinterpret_cast<uint4*>(Xs + col * HID + part * 16 + 8) = z4;
    }
    __syncthreads();
    if (tid < 56){
        int s = tid / 7, d = tid % 7;
        Xs[s * HID + (d ^ ((s & 7) << 3))] = (__bf16)qs[s][d];     // primal col: q
        int c = 8 + s * 7 + d;
        Xs[c * HID + (d ^ ((c & 7) << 3))] = (__bf16)1.0f;         // tangent col: e_d
    }
    __syncthreads();

    // ---- 3 MLP layers (layer0 K=32 via padded W0) ----
    mlp_layer<1>(wsb + OFF_W0, 32,  b0, Xs, sgbuf, w, lo, hi, scol, prim);
    mlp_layer<8>(wsb,          HID, b1, Xs, sgbuf, w, lo, hi, scol, prim);
    mlp_layer<8>(wsb + OFF_W2, HID, b2, Xs, sgbuf, w, lo, hi, scol, prim);

    // ---- heads: [48x256] @ X -> registers (waves 0..2) ----
    f32x4 hacc[4];
    #pragma unroll
    for (int ni = 0; ni < 4; ++ni) hacc[ni] = (f32x4){0.f,0.f,0.f,0.f};
    if (w < 3){
        const __bf16* Wh = wsb + OFF_WH;
        #pragma unroll 2
        for (int kk = 0; kk < 8; ++kk){
            const int k0 = kk * 32 + hi * 8;
            bf16x8 a = *reinterpret_cast<const bf16x8*>(Wh + (w * 16 + lo) * HID + k0);
            #pragma unroll
            for (int ni = 0; ni < 4; ++ni){
                int col = ni * 16 + lo;
                bf16x8 bfr = *reinterpret_cast<const bf16x8*>(Xs + col * HID + (k0 ^ ((col & 7) << 3)));
                hacc[ni] = __builtin_amdgcn_mfma_f32_16x16x32_bf16(a, bfr, hacc[ni], 0, 0, 0);
            }
        }
    }
    __syncthreads();            // Xs fully read; region becomes SCR + tail scratch

    float* SCR = (float*)LDSB;                  // [35][64]
    float* TB  = (float*)LDSB + 2304;           // tail scratch (offset 9216 B)
    #define LSA(s,i,j) TB[(s)*49+(i)*7+(j)]
    #define VSH(s,i,j) TB[392+(s)*49+(i)*7+(j)]
    #define LDT(s,i,j) TB[784+(s)*49+(i)*7+(j)]
    #define UB(s,k)    TB[1176+(s)*8+(k)]
    #define WB2(s,k)   TB[1240+(s)*8+(k)]
    #define SGL(s,k)   TB[1304+(s)*8+(k)]
    #define LDR(s,k)   TB[1368+(s)*8+(k)]

    if (w < 3){
        #pragma unroll
        for (int ni = 0; ni < 4; ++ni)
            #pragma unroll
            for (int r = 0; r < 4; ++r){
                int row = w * 16 + hi * 4 + r;
                if (row < 35) SCR[row * 64 + ni * 16 + lo] = hacc[ni][r];
            }
    }
    __syncthreads();

    // ---- analytic tail: 8 groups of 32 lanes, sample s = tid>>5 ----
    {
        const int s = tid >> 5;
        const int t = tid & 31;

        if (t < 7){
            int i = t;
            float lr = SCR[(7 + i) * 64 + s] + bld[i];
            LDR(s, i) = lr;
            SGL(s, i) = sigmoid_fast(lr);
            for (int j = 0; j < 7; ++j){
                float val;
                if (j == i)      val = softplus_fast(lr) + 1e-3f;
                else if (j < i)  val = SCR[(14 + (i*(i-1))/2 + j) * 64 + s] + blt[(i*(i-1))/2 + j];
                else             val = 0.f;
                LSA(s, i, j) = val;
            }
        }
        __syncthreads();

        auto LDQ = [&](int i, int j, int c)->float{
            if (i == j) return SGL(s, i) * SCR[(7 + i) * 64 + 8 + s * 7 + c];
            if (i >  j) return SCR[(14 + (i*(i-1))/2 + j) * 64 + 8 + s * 7 + c];
            return 0.f;
        };

        if (t < 7){
            float u = 0.f;
            for (int j = 0; j < 7; ++j) u = fmaf(qds_[s][j], LSA(s, j, t), u);
            UB(s, t) = u;
            for (int m = 0; m < 7; ++m){
                float v = 0.f;
                for (int j = 0; j < 7; ++j) v = fmaf(qds_[s][j], LDQ(j, m, t), v);
                VSH(s, m, t) = v;
            }
            for (int k = 0; k < 7; ++k){
                float a = 0.f;
                for (int c2 = 0; c2 < 7; ++c2) a = fmaf(LDQ(t, k, c2), qds_[s][c2], a);
                LDT(s, t, k) = a;
            }
        }
        __syncthreads();

        if (t < 7){
            float w2 = 0.f;
            for (int c2 = 0; c2 < 7; ++c2) w2 = fmaf(VSH(s, t, c2), qds_[s][c2], w2);
            WB2(s, t) = w2;
        }
        __syncthreads();

        if (t < 7){
            const int i  = t;
            const int Sg = s0g + s;
            float c1 = 0.f;
            for (int k = 0; k < 7; ++k)
                c1 += LSA(s, i, k) * WB2(s, k) + LDT(s, i, k) * UB(s, k);
            float qh = 0.f;
            for (int m = 0; m < 7; ++m) qh = fmaf(UB(s, m), VSH(s, m, i), qh);
            float cfin = c1 - qh;
            float hm[7];
            for (int j = 0; j < 7; ++j){
                float a = 0.f;
                for (int k = 0; k < 7; ++k) a = fmaf(LSA(s, i, k), LSA(s, j, k), a);
                hm[j] = a;
            }
            float gv  = SCR[i * 64 + s] + bg[i];
            float qdv = qds_[s][i];
            float fvc = fmaxf(fv[i], 1e-3f);
            float tf  = (fc[i] + fs[i] * __expf(-qdv * qdv / fvc)) * tanh_fast(100.0f * qdv) + fd[i] * qdv;
            float tp  = cfin + gv + tf;
            for (int j = 0; j < 7; ++j) tp = fmaf(hm[j], qdds_[s][j], tp);

            const int B = Btot;
            out[Sg * 7 + i] = tp;
            float* o1 = out + (size_t)B * 7;
            for (int j = 0; j < 7; ++j) o1[(size_t)Sg * 49 + i * 7 + j] = hm[j];
            out[(size_t)B * 56 + Sg * 7 + i] = cfin;
            out[(size_t)B * 63 + Sg * 7 + i] = gv;
            out[(size_t)B * 70 + Sg * 7 + i] = tf;
            out[(size_t)B * 77 + Sg * 7 + i] = LDR(s, i);
        }
    }
}

extern "C" void kernel_launch(void* const* d_in, const int* in_sizes, int n_in,
                              void* d_out, int out_size, void* d_ws, size_t ws_size,
                              hipStream_t stream) {
    const float* q   = (const float*)d_in[0];
    const float* qd  = (const float*)d_in[1];
    const float* qdd = (const float*)d_in[2];
    const float* W0  = (const float*)d_in[3];
    const float* b0  = (const float*)d_in[4];
    const float* W1  = (const float*)d_in[5];
    const float* b1  = (const float*)d_in[6];
    const float* W2  = (const float*)d_in[7];
    const float* b2  = (const float*)d_in[8];
    const float* Wg  = (const float*)d_in[9];
    const float* bg  = (const float*)d_in[10];
    const float* Wld = (const float*)d_in[11];
    const float* bld = (const float*)d_in[12];
    const float* Wlt = (const float*)d_in[13];
    const float* blt = (const float*)d_in[14];
    const float* fd  = (const float*)d_in[15];
    const float* fc  = (const float*)d_in[16];
    const float* fs  = (const float*)d_in[17];
    const float* fv  = (const float*)d_in[18];

    const int Btot = in_sizes[0] / NDOF;      // 32768
    __bf16* wsb = (__bf16*)d_ws;

    convert_weights<<<dim3(WS_TOT / 256), dim3(256), 0, stream>>>(W1, W2, Wg, Wld, Wlt, W0, wsb);
    dln_main<<<dim3(Btot / SPW), dim3(256), 0, stream>>>(q, qd, qdd, b0, b1, b2,
                                                         bg, bld, blt,
                                                         fd, fc, fs, fv,
                                                         wsb, (float*)d_out, Btot);
}